// Round 1
// 378.095 us; speedup vs baseline: 1.0562x; 1.0562x over previous
//
#include <hip/hip_runtime.h>

#define N_NEURONS   100000
#define INPUT_SIZE  1024
#define OUTPUT_SIZE 256
#define E_SYN       10000000
#define STEPS       3

#define RANGES      8
#define BIN         12500          // neurons per range; RANGES*BIN == N_NEURONS
#define SCAT_BLK    1024           // 2 blocks/CU -> 32 waves/CU (100% occupancy)
#define CBLK        64             // blocks per range in scatter
#define RG          8              // reduce groups (association-preserving fusion)
#define RSL         (CBLK / RG)    // 8 slabs per group
#define CAP         1280000        // per-range bucket capacity (mean 1.25M, ~28 sigma)
#define STG_CAP     128            // staging ring entries per range per wave
#define VEC4        (E_SYN / 4)

// partition pipeline geometry
#define CHK         2048           // edges per chunk (one wave per chunk)
#define NCH         4883           // ceil(E_SYN / CHK)
#define PITER       (CHK / (64 * 4))   // 8 int4 iterations per wave
#define HIST_GRID   ((NCH + 3) / 4)    // 4 waves (chunks) per 256-thr block
#define PART_GRID   ((NCH + 1) / 2)    // 2 waves (chunks) per 128-thr block

// v init
__global__ void init_state(const float* __restrict__ x, float* __restrict__ v) {
    int i = blockIdx.x * blockDim.x + threadIdx.x;
    if (i < N_NEURONS) v[i] = (i < INPUT_SIZE) ? x[i] : 0.0f;
}

// Per-chunk range histogram. One wave per 2048-edge chunk; lane r accumulates
// only range r's count via the shared ballot masks. Full occupancy, BW-bound.
__global__ __launch_bounds__(256) void hist_kernel(const int* __restrict__ dst,
                                                   int* __restrict__ hist) {
    const int lane  = threadIdx.x & 63;
    const int wv    = threadIdx.x >> 6;
    const int chunk = blockIdx.x * 4 + wv;
    if (chunk >= NCH) return;
    const long beg = (long)chunk * CHK;
    const int4* dst4 = (const int4*)dst;
    int h = 0;
    for (int it = 0; it < PITER; ++it) {
        long e  = beg + (long)(it * 64 + lane) * 4;
        bool ok = (e < E_SYN);
        int4 d4 = ok ? dst4[e >> 2] : make_int4(0, 0, 0, 0);
        unsigned long long okm = __ballot(ok);
        int rk[4] = {d4.x / BIN, d4.y / BIN, d4.z / BIN, d4.w / BIN};
#pragma unroll
        for (int k = 0; k < 4; ++k) {
            unsigned long long b0 = __ballot(rk[k] & 1);
            unsigned long long b1 = __ballot(rk[k] & 2);
            unsigned long long b2 = __ballot(rk[k] & 4);
            unsigned long long m = ((lane & 1) ? b0 : ~b0) &
                                   ((lane & 2) ? b1 : ~b1) &
                                   ((lane & 4) ? b2 : ~b2) & okm;
            h += __popcll(m);
        }
    }
    if (lane < RANGES) hist[(size_t)lane * NCH + chunk] = h;
}

// Exclusive scan per range over chunk counts -> exact dense bases (no atomics,
// fully deterministic bucket layout) + per-range totals for scatter.
__global__ __launch_bounds__(1024) void scan_kernel(const int* __restrict__ hist,
                                                    int* __restrict__ bases,
                                                    int* __restrict__ gcur) {
    const int r = blockIdx.x;
    const int t = threadIdx.x;
    const int lane = t & 63;
    const int wv   = t >> 6;
    int vals[5];
    int s = 0;
#pragma unroll
    for (int j = 0; j < 5; ++j) {
        int idx = t * 5 + j;
        int vv  = (idx < NCH) ? hist[(size_t)r * NCH + idx] : 0;
        vals[j] = vv;
        s += vv;
    }
    // inclusive wave scan of s
    int x = s;
#pragma unroll
    for (int d = 1; d < 64; d <<= 1) {
        int y = __shfl_up(x, d, 64);
        if (lane >= d) x += y;
    }
    __shared__ int wsum[16];
    if (lane == 63) wsum[wv] = x;
    __syncthreads();
    if (wv == 0) {
        int y = (lane < 16) ? wsum[lane] : 0;
        int z = y;
#pragma unroll
        for (int d = 1; d < 16; d <<= 1) {
            int u = __shfl_up(z, d, 64);
            if (lane >= d) z += u;
        }
        if (lane < 16) wsum[lane] = z - y;   // exclusive wave offsets
    }
    __syncthreads();
    int run = (x - s) + wsum[wv];            // exclusive prefix for this thread
#pragma unroll
    for (int j = 0; j < 5; ++j) {
        int idx = t * 5 + j;
        if (idx < NCH) bases[(size_t)r * NCH + idx] = r * CAP + run;
        run += vals[j];
    }
    if (t == 1023) gcur[r] = run;            // total count of range r
}

// Partition into range-major buckets of packed 8B records. One wave per chunk,
// no block barriers. Ring cursors live in lane registers (lane r owns range r):
// base select = one shfl, cursor update = own-range popc on 8 lanes, flush
// check = one ballot + sparse bit loop. All record writes are dense 512B bursts.
__global__ __launch_bounds__(128) void partition_kernel(
        const float* __restrict__ w,
        const int*   __restrict__ src,
        const int*   __restrict__ dst,
        const int*   __restrict__ bases,
        int2* __restrict__ recs) {
    __shared__ int2 stg[2][RANGES][STG_CAP];
    const int lane  = threadIdx.x & 63;
    const int wv    = threadIdx.x >> 6;
    const int chunk = blockIdx.x * 2 + wv;
    if (chunk >= NCH) return;
    const unsigned long long ltmask = (1ull << lane) - 1ull;

    int cur = 0, wrr = 0, flr = 0;           // lane r holds range r's cursors
    if (lane < RANGES) cur = bases[(size_t)lane * NCH + chunk];

    const long beg = (long)chunk * CHK;
    const int4* dst4 = (const int4*)dst;
    const int4* src4 = (const int4*)src;
    const int4* wq4  = (const int4*)w;

    for (int it = 0; it < PITER; ++it) {
        long e  = beg + (long)(it * 64 + lane) * 4;
        bool ok = (e < E_SYN);
        int4 d4 = ok ? dst4[e >> 2] : make_int4(0, 0, 0, 0);
        int4 s4 = ok ? src4[e >> 2] : make_int4(0, 0, 0, 0);
        int4 q4 = ok ? wq4[e >> 2]  : make_int4(0, 0, 0, 0);
        unsigned long long okm = __ballot(ok);
        int dd[4] = {d4.x, d4.y, d4.z, d4.w};
        int ss[4] = {s4.x, s4.y, s4.z, s4.w};
        int qq[4] = {q4.x, q4.y, q4.z, q4.w};
#pragma unroll
        for (int k = 0; k < 4; ++k) {
            int d = dd[k];
            int r = d / BIN;
            unsigned long long b0 = __ballot(r & 1);
            unsigned long long b1 = __ballot(r & 2);
            unsigned long long b2 = __ballot(r & 4);
            unsigned long long mym = ((r & 1) ? b0 : ~b0) &
                                     ((r & 2) ? b1 : ~b1) &
                                     ((r & 4) ? b2 : ~b2) & okm;
            int rank  = __popcll(mym & ltmask);
            int wslot = __shfl(wrr, r, 64);
            int slot  = (wslot + rank) & (STG_CAP - 1);
            if (ok) stg[wv][r][slot] = make_int2((ss[k] << 14) | (d - r * BIN), qq[k]);
            // own-range cursor update (only lanes 0..7 meaningful)
            unsigned long long mm = ((lane & 1) ? b0 : ~b0) &
                                    ((lane & 2) ? b1 : ~b1) &
                                    ((lane & 4) ? b2 : ~b2) & okm;
            wrr += __popcll(mm);
            // flush any range with >=64 pending (at most one per range per k)
            unsigned long long fb = __ballot(wrr - flr >= 64) & 0xFFull;
            while (fb) {
                int rr = __ffsll((long long)fb) - 1;
                fb &= fb - 1;
                int gpos = __shfl(cur, rr, 64);
                int f0   = __shfl(flr, rr, 64) & (STG_CAP - 1);   // 64-aligned, no wrap
                int2 rec = stg[wv][rr][f0 + lane];
                recs[(size_t)gpos + lane] = rec;
                if (lane == rr) { flr += 64; cur += 64; }
            }
        }
    }
    // drain remainders (<64 each, 64-aligned fl -> no ring wrap)
#pragma unroll
    for (int rr = 0; rr < RANGES; ++rr) {
        int wt = __shfl(wrr, rr, 64);
        int ft = __shfl(flr, rr, 64);
        int pend = wt - ft;
        if (pend > 0) {
            int gpos = __shfl(cur, rr, 64);
            if (lane < pend)
                recs[(size_t)gpos + lane] = stg[wv][rr][(ft & (STG_CAP - 1)) + lane];
        }
    }
}

// Per step: block (r,c) streams a stripe of bucket r (2 packed edges per int4,
// 4x unrolled), LDS-bins, flushes partial slab. 1024 thr -> 32 waves/CU.
__global__ __launch_bounds__(SCAT_BLK) void scatter_sorted(
        const int2* __restrict__ recs,
        const int*  __restrict__ gcur,
        const float* __restrict__ v,
        float* __restrict__ partials) {
    __shared__ float bins[BIN];
    const int r = blockIdx.x / CBLK;
    const int c = blockIdx.x % CBLK;
    for (int j = threadIdx.x; j < BIN; j += SCAT_BLK) bins[j] = 0.0f;
    __syncthreads();

    const int cnt   = gcur[r];
    const int npair = cnt >> 1;
    const int4* base4 = (const int4*)(recs + (size_t)r * CAP);
    const int stride = CBLK * SCAT_BLK;
    int u = c * SCAT_BLK + threadIdx.x;
    for (; u + 3 * stride < npair; u += 4 * stride) {
        int4 a = base4[u];
        int4 b = base4[u + stride];
        int4 e = base4[u + 2 * stride];
        int4 f = base4[u + 3 * stride];
        float va0 = v[a.x >> 14];
        float va1 = v[a.z >> 14];
        float vb0 = v[b.x >> 14];
        float vb1 = v[b.z >> 14];
        float ve0 = v[e.x >> 14];
        float ve1 = v[e.z >> 14];
        float vf0 = v[f.x >> 14];
        float vf1 = v[f.z >> 14];
        atomicAdd(&bins[a.x & 16383], va0 * __int_as_float(a.y));
        atomicAdd(&bins[a.z & 16383], va1 * __int_as_float(a.w));
        atomicAdd(&bins[b.x & 16383], vb0 * __int_as_float(b.y));
        atomicAdd(&bins[b.z & 16383], vb1 * __int_as_float(b.w));
        atomicAdd(&bins[e.x & 16383], ve0 * __int_as_float(e.y));
        atomicAdd(&bins[e.z & 16383], ve1 * __int_as_float(e.w));
        atomicAdd(&bins[f.x & 16383], vf0 * __int_as_float(f.y));
        atomicAdd(&bins[f.z & 16383], vf1 * __int_as_float(f.w));
    }
    for (; u < npair; u += stride) {
        int4 a = base4[u];
        atomicAdd(&bins[a.x & 16383], v[a.x >> 14] * __int_as_float(a.y));
        atomicAdd(&bins[a.z & 16383], v[a.z >> 14] * __int_as_float(a.w));
    }
    if ((cnt & 1) && c == 0 && threadIdx.x == 0) {
        int2 p = recs[(size_t)r * CAP + cnt - 1];
        atomicAdd(&bins[p.x & 16383], v[p.x >> 14] * __int_as_float(p.y));
    }
    __syncthreads();
    float* o = partials + (size_t)(r * CBLK + c) * BIN;
    for (int j = threadIdx.x; j < BIN; j += SCAT_BLK) o[j] = bins[j];
}

// Fused reduce: sum 64 slabs with the SAME association as the old two-stage
// tree (8 sequential groups of 8 sequential slabs -> bitwise identical),
// then bias + tanh (except outputs). Removes the p2 round-trip + a launch.
__global__ void reduce_fused(const float* __restrict__ partials,
                             const float* __restrict__ bias,
                             float* __restrict__ v,
                             float* __restrict__ out,
                             int write_out) {
    int i4 = 4 * (blockIdx.x * blockDim.x + threadIdx.x);
    if (i4 >= N_NEURONS) return;
    const int r = i4 / BIN;
    const int j = i4 - r * BIN;
    const float* base = partials + (size_t)(r * CBLK) * BIN + j;
    float4 tot = {0.f, 0.f, 0.f, 0.f};
#pragma unroll 2
    for (int g = 0; g < RG; ++g) {
        float4 a = {0.f, 0.f, 0.f, 0.f};
#pragma unroll
        for (int cc = 0; cc < RSL; ++cc) {
            float4 p = *(const float4*)(base + (size_t)(g * RSL + cc) * BIN);
            a.x += p.x; a.y += p.y; a.z += p.z; a.w += p.w;
        }
        tot.x += a.x; tot.y += a.y; tot.z += a.z; tot.w += a.w;
    }
    float av[4] = {tot.x, tot.y, tot.z, tot.w};
#pragma unroll
    for (int k = 0; k < 4; ++k) {
        int i = i4 + k;
        float val = av[k] + ((i >= INPUT_SIZE) ? bias[i - INPUT_SIZE] : 0.0f);
        float nv  = (i < N_NEURONS - OUTPUT_SIZE) ? tanhf(val) : val;
        v[i] = nv;
        if (write_out && i >= N_NEURONS - OUTPUT_SIZE)
            out[i - (N_NEURONS - OUTPUT_SIZE)] = val;
    }
}

// ---- fallback (small ws): multi-pass binned rescan path ----
__global__ void scatter_binned(const float* __restrict__ w,
                               const int*   __restrict__ src,
                               const int*   __restrict__ dst,
                               const float* __restrict__ v,
                               float*       __restrict__ partials,
                               int C) {
    __shared__ float bins[BIN];
    const int r = blockIdx.x / C;
    const int c = blockIdx.x % C;
    const int lo = r * BIN;
    const int hi = lo + BIN;
    for (int j = threadIdx.x; j < BIN; j += blockDim.x) bins[j] = 0.0f;
    __syncthreads();
    const int4*   src4 = (const int4*)src;
    const int4*   dst4 = (const int4*)dst;
    const float4* w4v  = (const float4*)w;
    const int stride = C * blockDim.x;
    for (int u = c * blockDim.x + threadIdx.x; u < VEC4; u += stride) {
        const int4   s4 = src4[u];
        const int4   d4 = dst4[u];
        const float4 wv = w4v[u];
        int   s[4] = {s4.x, s4.y, s4.z, s4.w};
        int   d[4] = {d4.x, d4.y, d4.z, d4.w};
        float ww[4] = {wv.x, wv.y, wv.z, wv.w};
#pragma unroll
        for (int k = 0; k < 4; ++k)
            if (d[k] >= lo && d[k] < hi)
                atomicAdd(&bins[d[k] - lo], v[s[k]] * ww[k]);
    }
    __syncthreads();
    float* o = partials + ((size_t)(r * C + c)) * BIN;
    for (int j = threadIdx.x; j < BIN; j += blockDim.x) o[j] = bins[j];
}
__global__ void reduce_update_fb(const float* __restrict__ partials,
                                 const float* __restrict__ bias,
                                 float* __restrict__ v,
                                 float* __restrict__ out,
                                 int C, int write_out) {
    int i4 = 4 * (blockIdx.x * blockDim.x + threadIdx.x);
    if (i4 >= N_NEURONS) return;
    const int r = i4 / BIN;
    const int j = i4 - r * BIN;
    const float* base = partials + ((size_t)r * C) * BIN + j;
    float4 acc = {0.f, 0.f, 0.f, 0.f};
    for (int c = 0; c < C; ++c) {
        float4 p = *(const float4*)(base + (size_t)c * BIN);
        acc.x += p.x; acc.y += p.y; acc.z += p.z; acc.w += p.w;
    }
    float av[4] = {acc.x, acc.y, acc.z, acc.w};
#pragma unroll
    for (int k = 0; k < 4; ++k) {
        int i = i4 + k;
        float val = av[k] + ((i >= INPUT_SIZE) ? bias[i - INPUT_SIZE] : 0.0f);
        float nv  = (i < N_NEURONS - OUTPUT_SIZE) ? tanhf(val) : val;
        v[i] = nv;
        if (write_out && i >= N_NEURONS - OUTPUT_SIZE)
            out[i - (N_NEURONS - OUTPUT_SIZE)] = val;
    }
}

extern "C" void kernel_launch(void* const* d_in, const int* in_sizes, int n_in,
                              void* d_out, int out_size, void* d_ws, size_t ws_size,
                              hipStream_t stream) {
    const float* x    = (const float*)d_in[0];
    const float* w    = (const float*)d_in[1];
    const float* bias = (const float*)d_in[2];
    const int*   src  = (const int*)d_in[3];
    const int*   dst  = (const int*)d_in[4];
    float* out = (float*)d_out;

    const int blk = 256;
    const int grid_n   = (N_NEURONS + blk - 1) / blk;
    const int red_grid = (N_NEURONS / 4 + blk - 1) / blk;

    // sorted-path ws layout: v | partials | hist | bases | recs | gcur
    float* v        = (float*)d_ws;
    float* partials = v + N_NEURONS;
    int*   hist     = (int*)(partials + (size_t)RANGES * CBLK * BIN);
    int*   bases    = hist + (size_t)RANGES * NCH;
    int2*  recs     = (int2*)(bases + (size_t)RANGES * NCH);
    int*   gcur     = (int*)(recs + (size_t)RANGES * CAP);
    size_t need = (size_t)((char*)(gcur + RANGES) - (char*)d_ws);

    if (ws_size >= need) {
        init_state<<<grid_n, blk, 0, stream>>>(x, v);
        hist_kernel<<<HIST_GRID, 256, 0, stream>>>(dst, hist);
        scan_kernel<<<RANGES, 1024, 0, stream>>>(hist, bases, gcur);
        partition_kernel<<<PART_GRID, 128, 0, stream>>>(w, src, dst, bases, recs);
        for (int s = 0; s < STEPS; ++s) {
            scatter_sorted<<<RANGES * CBLK, SCAT_BLK, 0, stream>>>(
                recs, gcur, v, partials);
            reduce_fused<<<red_grid, blk, 0, stream>>>(
                partials, bias, v, out, s == STEPS - 1 ? 1 : 0);
        }
    } else {
        long C = (long)(ws_size / 4 / N_NEURONS) - 1;
        if (C > 64) C = 64;
        if (C < 1) C = 1;
        float* part_fb = v + N_NEURONS;
        init_state<<<grid_n, blk, 0, stream>>>(x, v);
        for (int s = 0; s < STEPS; ++s) {
            scatter_binned<<<RANGES * (int)C, SCAT_BLK, 0, stream>>>(
                w, src, dst, v, part_fb, (int)C);
            reduce_update_fb<<<red_grid, blk, 0, stream>>>(
                part_fb, bias, v, out, (int)C, s == STEPS - 1 ? 1 : 0);
        }
    }
}